// Round 7
// baseline (2575.603 us; speedup 1.0000x reference)
//
#include <hip/hip_runtime.h>
#include <math.h>

#define NPTS 4096
#define NBATCH 4
#define NTOT (NBATCH*NPTS)
#define KNN 20
#define NCHUNK 8
#define CHUNK (NPTS/NCHUNK)

__device__ __forceinline__ float lrelu_f(float h) { return h >= 0.f ? h : 0.2f * h; }

__device__ __forceinline__ void fma4(float4& acc, float s, const float4& b) {
    acc.x += s * b.x; acc.y += s * b.y; acc.z += s * b.z; acc.w += s * b.w;
}

// ---------------- x:(B,6,N) -> xyzT:(B*N,6) ----------------
__global__ __launch_bounds__(256) void k_transpose_in(const float* __restrict__ x, float* __restrict__ xyzT)
{
    int p = blockIdx.x * 256 + threadIdx.x;
    if (p >= NTOT) return;
    int b = p >> 12, n = p & (NPTS - 1);
    #pragma unroll
    for (int c = 0; c < 6; ++c)
        xyzT[(size_t)p * 6 + c] = x[((size_t)b * 6 + c) * NPTS + n];
}

// ---------------- row squared norms ----------------
__global__ __launch_bounds__(256) void k_row_norms(const float* __restrict__ f, int stride, int C, float* __restrict__ xx)
{
    int p = blockIdx.x * 256 + threadIdx.x;
    if (p >= NTOT) return;
    const float* r = f + (size_t)p * stride;
    float s = 0.f;
    for (int c = 0; c < C; ++c) { float v = r[c]; s += v * v; }
    xx[p] = s;
}

// ---------------- weight transpose (O,CK) -> (CK,O) ----------------
__global__ __launch_bounds__(256) void k_transpose_w(const float* __restrict__ w, float* __restrict__ wt, int O, int CK)
{
    int e = blockIdx.x * 256 + threadIdx.x;
    if (e >= O * CK) return;
    int c = e / O, o = e - c * O;
    wt[e] = w[(size_t)o * CK + c];
}

// ---------------- kNN tile: 64 queries x 512-cand chunk, GEMM-style dots + tiled selection ----
// CC = padded channel count (4 for C=3, 64 for C=64). Values compared: 2*dot - ||c||^2
// (dropping per-query ||q||^2 preserves ordering and ties). Strict-> insertion over
// ascending candidate index keeps jax.lax.top_k tie semantics (lower index first).
template<int CC>
__global__ __launch_bounds__(256) void k_knn_tile(
    const float* __restrict__ feat, int fstride, int creal,
    const float* __restrict__ xx,
    float* __restrict__ pval, int* __restrict__ pidx)
{
    constexpr int PAD = 68;
    constexpr int S1 = 64 * PAD + CC * PAD + 64 * PAD + 64;
    constexpr int SM = (S1 > 10240) ? S1 : 10240;
    __shared__ float smem[SM];
    float* qs   = smem;                    // [64][PAD] queries, row-major
    float* cs   = smem + 64 * PAD;         // [CC][PAD] candidates, column-major (k-major)
    float* dist = cs + CC * PAD;           // [64 q][PAD] dot tile
    float* sxx  = dist + 64 * PAD;         // [64] candidate norms

    int tid = threadIdx.x;
    int qbase = blockIdx.x * 64;           // global point id of first query (64 | 4096)
    int b = qbase >> 12;
    int chunk = blockIdx.y;
    int cbase = chunk * CHUNK;             // candidate base within batch
    const float* fb = feat + (size_t)b * NPTS * fstride;
    const float* xb = xx + b * NPTS;

    // ---- stage queries ----
    if constexpr (CC == 64) {
        for (int e = tid; e < 64 * 16; e += 256) {
            int row = e >> 4, c4 = e & 15;
            float4 v = *(const float4*)(feat + (size_t)(qbase + row) * fstride + 4 * c4);
            *(float4*)&qs[row * PAD + 4 * c4] = v;
        }
    } else {
        if (tid < 64) {
            const float* r = feat + (size_t)(qbase + tid) * fstride;
            qs[tid * PAD + 0] = r[0]; qs[tid * PAD + 1] = r[1];
            qs[tid * PAD + 2] = r[2]; qs[tid * PAD + 3] = 0.f;
        }
    }

    int q = tid & 63, s = tid >> 6;        // scan role: 4 sub-scanners per query
    int qg = tid >> 4, cg = tid & 15;      // gemm role: 4x4 micro-tile

    float lv[KNN]; int li[KNN];
    #pragma unroll
    for (int j = 0; j < KNN; ++j) { lv[j] = -INFINITY; li[j] = 0x7fffffff; }

    for (int t0 = 0; t0 < CHUNK; t0 += 64) {
        __syncthreads();
        // ---- stage candidate tile, column-major ----
        if constexpr (CC == 64) {
            for (int e = tid; e < 64 * 16; e += 256) {
                int c = e & 63, k4 = e >> 6;
                float4 v = *(const float4*)(fb + (size_t)(cbase + t0 + c) * fstride + 4 * k4);
                cs[(4 * k4 + 0) * PAD + c] = v.x;
                cs[(4 * k4 + 1) * PAD + c] = v.y;
                cs[(4 * k4 + 2) * PAD + c] = v.z;
                cs[(4 * k4 + 3) * PAD + c] = v.w;
            }
        } else {
            if (tid < 64) {
                const float* r = fb + (size_t)(cbase + t0 + tid) * fstride;
                cs[0 * PAD + tid] = r[0]; cs[1 * PAD + tid] = r[1];
                cs[2 * PAD + tid] = r[2]; cs[3 * PAD + tid] = 0.f;
            }
        }
        if (tid < 64) sxx[tid] = xb[cbase + t0 + tid];
        __syncthreads();

        // ---- GEMM: acc[i] (float4 over 4 cands) for 4 queries ----
        float4 acc0 = {0,0,0,0}, acc1 = {0,0,0,0}, acc2 = {0,0,0,0}, acc3 = {0,0,0,0};
        #pragma unroll
        for (int kk = 0; kk < CC / 4; ++kk) {
            float4 a0 = *(const float4*)&qs[(qg * 4 + 0) * PAD + 4 * kk];
            float4 a1 = *(const float4*)&qs[(qg * 4 + 1) * PAD + 4 * kk];
            float4 a2 = *(const float4*)&qs[(qg * 4 + 2) * PAD + 4 * kk];
            float4 a3 = *(const float4*)&qs[(qg * 4 + 3) * PAD + 4 * kk];
            float4 b0 = *(const float4*)&cs[(4 * kk + 0) * PAD + cg * 4];
            float4 b1 = *(const float4*)&cs[(4 * kk + 1) * PAD + cg * 4];
            float4 b2 = *(const float4*)&cs[(4 * kk + 2) * PAD + cg * 4];
            float4 b3 = *(const float4*)&cs[(4 * kk + 3) * PAD + cg * 4];
            fma4(acc0, a0.x, b0); fma4(acc0, a0.y, b1); fma4(acc0, a0.z, b2); fma4(acc0, a0.w, b3);
            fma4(acc1, a1.x, b0); fma4(acc1, a1.y, b1); fma4(acc1, a1.z, b2); fma4(acc1, a1.w, b3);
            fma4(acc2, a2.x, b0); fma4(acc2, a2.y, b1); fma4(acc2, a2.z, b2); fma4(acc2, a2.w, b3);
            fma4(acc3, a3.x, b0); fma4(acc3, a3.y, b1); fma4(acc3, a3.z, b2); fma4(acc3, a3.w, b3);
        }
        *(float4*)&dist[(qg * 4 + 0) * PAD + cg * 4] = acc0;
        *(float4*)&dist[(qg * 4 + 1) * PAD + cg * 4] = acc1;
        *(float4*)&dist[(qg * 4 + 2) * PAD + cg * 4] = acc2;
        *(float4*)&dist[(qg * 4 + 3) * PAD + cg * 4] = acc3;
        __syncthreads();

        // ---- selection: 4 sub-scanners per query, 16 cands each, ascending index ----
        const float* drow = &dist[q * PAD + s * 16];
        #pragma unroll 4
        for (int cc = 0; cc < 16; ++cc) {
            float cv = 2.f * drow[cc] - sxx[s * 16 + cc];
            if (cv > lv[KNN - 1]) {
                int ci = cbase + t0 + s * 16 + cc;
                #pragma unroll
                for (int j = 0; j < KNN; ++j) {
                    bool sw = cv > lv[j];
                    float tf = lv[j]; int ti = li[j];
                    lv[j] = sw ? cv : lv[j];  li[j] = sw ? ci : li[j];
                    cv    = sw ? tf : cv;     ci    = sw ? ti : ci;
                }
            }
        }
    }

    // ---- sub-merge: 4 sorted 20-lists per query -> one sorted 20-list ----
    __syncthreads();
    float* mv = smem;                      // [256][20] values (qs/cs/dist dead)
    int*   mi = (int*)(smem + 5120);       // [256][20] indices
    #pragma unroll
    for (int j = 0; j < KNN; ++j) {
        mv[(q * 4 + s) * KNN + j] = lv[j];
        mi[(q * 4 + s) * KNN + j] = li[j];
    }
    __syncthreads();
    if (tid < 64) {
        int p = qbase + tid;
        int hp[4] = {0, 0, 0, 0};
        size_t obase = ((size_t)p * NCHUNK + chunk) * KNN;
        #pragma unroll 1
        for (int r = 0; r < KNN; ++r) {
            float bv = -INFINITY; int bi = 0x7fffffff; int bs = 0;
            #pragma unroll
            for (int c = 0; c < 4; ++c) {
                if (hp[c] < KNN) {
                    float v = mv[(tid * 4 + c) * KNN + hp[c]];
                    int  ii = mi[(tid * 4 + c) * KNN + hp[c]];
                    if (v > bv || (v == bv && ii < bi)) { bv = v; bi = ii; bs = c; }
                }
            }
            pval[obase + r] = bv;
            pidx[obase + r] = bi;
            hp[bs]++;
        }
    }
}

// ---------------- kNN merge: one thread per query, 8-way merge of sorted 20-lists ----------------
__global__ __launch_bounds__(256) void k_knn_merge(
    const float* __restrict__ pval, const int* __restrict__ pidx,
    int* __restrict__ idx_out)
{
    int p = blockIdx.x * 256 + threadIdx.x;
    if (p >= NTOT) return;
    const float* pv = pval + (size_t)p * NCHUNK * KNN;
    const int*   pi = pidx + (size_t)p * NCHUNK * KNN;
    float hv[NCHUNK]; int hi_[NCHUNK]; int hp[NCHUNK];
    #pragma unroll
    for (int c = 0; c < NCHUNK; ++c) { hv[c] = pv[c * KNN]; hi_[c] = pi[c * KNN]; hp[c] = 0; }
    #pragma unroll 1
    for (int r = 0; r < KNN; ++r) {
        float bv = hv[0]; int bi = hi_[0]; int bc = 0;
        #pragma unroll
        for (int c = 1; c < NCHUNK; ++c) {
            if (hv[c] > bv || (hv[c] == bv && hi_[c] < bi)) { bv = hv[c]; bi = hi_[c]; bc = c; }
        }
        idx_out[(size_t)p * KNN + r] = bi;
        #pragma unroll
        for (int c = 0; c < NCHUNK; ++c) {
            if (c == bc) {
                hp[c]++;
                if (hp[c] < KNN) { hv[c] = pv[c * KNN + hp[c]]; hi_[c] = pi[c * KNN + hp[c]]; }
                else             { hv[c] = -INFINITY;           hi_[c] = 0x7fffffff; }
            }
        }
    }
}

// ---------------- edge conv: one block per point ----------------
// out[o] = lrelu( s[o]*(dot_sel + q[o]) + d[o] ),  dot_sel = max_k (s>=0) or min_k (s<0)
template<int C, int O>
__global__ __launch_bounds__(256) void k_edge_conv(
    const float* __restrict__ in, int istride,
    const int* __restrict__ idx,
    const float* __restrict__ wt,   // (2C, O) transposed weights
    const float* __restrict__ gg, const float* __restrict__ bb,
    const float* __restrict__ mm, const float* __restrict__ vv,
    float* __restrict__ out, int ostride)
{
    constexpr int G = 256 / O;
    constexpr int KPT = KNN / G;
    __shared__ int   sidx[KNN];
    __shared__ float sctr[C];
    __shared__ float snbr[KNN][C];
    __shared__ float sred[2][256];
    int p = blockIdx.x;
    int b = p >> 12;
    int tid = threadIdx.x;
    const float* ctr_row = in + (size_t)p * istride;
    if (tid < KNN) sidx[tid] = idx[(size_t)p * KNN + tid];
    for (int e = tid; e < C; e += 256) sctr[e] = ctr_row[e];
    __syncthreads();
    for (int e = tid; e < KNN * C; e += 256) {
        int k = e / C, c = e - k * C;
        snbr[k][c] = in[((size_t)b * NPTS + sidx[k]) * istride + c];
    }
    __syncthreads();
    int o = tid % O, gid = tid / O;
    float q = 0.f;
    #pragma unroll 4
    for (int c = 0; c < C; ++c) q += (wt[(C + c) * O + o] - wt[c * O + o]) * sctr[c];
    float acc[KPT];
    #pragma unroll
    for (int k = 0; k < KPT; ++k) acc[k] = 0.f;
    #pragma unroll 4
    for (int c = 0; c < C; ++c) {
        float wv = wt[c * O + o];
        #pragma unroll
        for (int k = 0; k < KPT; ++k) acc[k] += wv * snbr[gid * KPT + k][c];
    }
    float mx = -INFINITY, mn = INFINITY;
    #pragma unroll
    for (int k = 0; k < KPT; ++k) { mx = fmaxf(mx, acc[k]); mn = fminf(mn, acc[k]); }
    sred[0][tid] = mx; sred[1][tid] = mn;
    __syncthreads();
    if (gid == 0) {
        #pragma unroll
        for (int g2 = 1; g2 < G; ++g2) { mx = fmaxf(mx, sred[0][g2 * O + o]); mn = fminf(mn, sred[1][g2 * O + o]); }
        float s = gg[o] * rsqrtf(vv[o] + 1e-5f);
        float d = bb[o] - mm[o] * s;
        float dotv = (s >= 0.f) ? mx : mn;
        float h = s * (dotv + q) + d;
        out[(size_t)p * ostride + o] = lrelu_f(h);
    }
}

// ---------------- color MLP (3 -> 64) ----------------
__global__ __launch_bounds__(256) void k_color(
    const float* __restrict__ xyzT,
    const float* __restrict__ w,
    const float* __restrict__ gg, const float* __restrict__ bb,
    const float* __restrict__ mm, const float* __restrict__ vv,
    float* __restrict__ out, int ostride)
{
    int t = blockIdx.x * 256 + threadIdx.x;
    int p = t >> 6, o = t & 63;
    if (p >= NTOT) return;
    const float* rgb = xyzT + (size_t)p * 6 + 3;
    float h = rgb[0] * w[o*3+0] + rgb[1] * w[o*3+1] + rgb[2] * w[o*3+2];
    float s = gg[o] * rsqrtf(vv[o] + 1e-5f);
    float d = bb[o] - mm[o] * s;
    out[(size_t)p * ostride + o] = lrelu_f(s * h + d);
}

// ---------------- fp32 tiled GEMM: out[m][o] = act( A[m][:] . W[o][:] ) ----------------
__global__ __launch_bounds__(256) void k_gemm(
    const float* __restrict__ A, int lda,
    const float* __restrict__ W,
    const float* __restrict__ gg, const float* __restrict__ bb,
    const float* __restrict__ mm, const float* __restrict__ vv,
    int bn_act,
    float* __restrict__ out, int ldo,
    int K, int O)
{
    __shared__ __align__(16) float As[16][68];
    __shared__ __align__(16) float Bs[16][68];
    int tid = threadIdx.x;
    int tM = blockIdx.x * 64;
    int tN = blockIdx.y * 64;
    int lk = tid & 15, lr = tid >> 4;
    float acc[4][4];
    #pragma unroll
    for (int i = 0; i < 4; ++i)
        #pragma unroll
        for (int j = 0; j < 4; ++j) acc[i][j] = 0.f;

    for (int k0 = 0; k0 < K; k0 += 16) {
        #pragma unroll
        for (int i = 0; i < 4; ++i) {
            int r = lr + 16 * i;
            As[lk][r] = A[(size_t)(tM + r) * lda + k0 + lk];
        }
        #pragma unroll
        for (int i = 0; i < 4; ++i) {
            int r = lr + 16 * i;
            int oo = tN + r;
            Bs[lk][r] = (oo < O) ? W[(size_t)oo * K + k0 + lk] : 0.f;
        }
        __syncthreads();
        #pragma unroll
        for (int kk = 0; kk < 16; ++kk) {
            float4 av = *(const float4*)&As[kk][lr * 4];
            float4 bv = *(const float4*)&Bs[kk][lk * 4];
            float a0 = av.x, a1 = av.y, a2 = av.z, a3 = av.w;
            float b0 = bv.x, b1 = bv.y, b2 = bv.z, b3 = bv.w;
            acc[0][0] += a0*b0; acc[0][1] += a0*b1; acc[0][2] += a0*b2; acc[0][3] += a0*b3;
            acc[1][0] += a1*b0; acc[1][1] += a1*b1; acc[1][2] += a1*b2; acc[1][3] += a1*b3;
            acc[2][0] += a2*b0; acc[2][1] += a2*b1; acc[2][2] += a2*b2; acc[2][3] += a2*b3;
            acc[3][0] += a3*b0; acc[3][1] += a3*b1; acc[3][2] += a3*b2; acc[3][3] += a3*b3;
        }
        __syncthreads();
    }
    int ty = lr, tx = lk;
    #pragma unroll
    for (int i = 0; i < 4; ++i) {
        int m = tM + ty * 4 + i;
        #pragma unroll
        for (int j = 0; j < 4; ++j) {
            int oo = tN + tx * 4 + j;
            if (oo < O) {
                float t = acc[i][j];
                if (bn_act) {
                    float s = gg[oo] * rsqrtf(vv[oo] + 1e-5f);
                    float d = bb[oo] - mm[oo] * s;
                    t = s * t + d;
                    t = t >= 0.f ? t : 0.2f * t;
                } else {
                    t += bb[oo];
                }
                out[(size_t)m * ldo + oo] = t;
            }
        }
    }
}

// ---------------- x5 (B*N,1024 cols of xcomb) -> d_out (B,1024,N) ----------------
__global__ __launch_bounds__(256) void k_transpose_x5(const float* __restrict__ xcomb, float* __restrict__ out_x5)
{
    __shared__ float t[64][65];
    int tM = blockIdx.x * 64;
    int tO = blockIdx.y * 64;
    int tid = threadIdx.x;
    #pragma unroll
    for (int i = 0; i < 16; ++i) {
        int e = tid + 256 * i;
        int rr = e >> 6, cc = e & 63;
        t[rr][cc] = xcomb[(size_t)(tM + rr) * 1408 + 384 + tO + cc];
    }
    __syncthreads();
    int b = tM >> 12, n0 = tM & (NPTS - 1);
    #pragma unroll
    for (int i = 0; i < 16; ++i) {
        int e = tid + 256 * i;
        int oo = e >> 6, nn = e & 63;
        out_x5[(size_t)b * 1024 * NPTS + (size_t)(tO + oo) * NPTS + n0 + nn] = t[nn][oo];
    }
}

extern "C" void kernel_launch(void* const* d_in, const int* in_sizes, int n_in,
                              void* d_out, int out_size, void* d_ws, size_t ws_size,
                              hipStream_t stream)
{
    const float* x = (const float*)d_in[0];
    // ec1:1-5  ec2:6-10  ec3:11-15  ec4:16-20  col:21-25  c5:26-30  c6:31-35  c7:36-40  c8:41-42
    const float* ew[4] = {(const float*)d_in[1],  (const float*)d_in[6],  (const float*)d_in[11], (const float*)d_in[16]};
    const float* eg[4] = {(const float*)d_in[2],  (const float*)d_in[7],  (const float*)d_in[12], (const float*)d_in[17]};
    const float* ebp[4]= {(const float*)d_in[3],  (const float*)d_in[8],  (const float*)d_in[13], (const float*)d_in[18]};
    const float* em[4] = {(const float*)d_in[4],  (const float*)d_in[9],  (const float*)d_in[14], (const float*)d_in[19]};
    const float* ev[4] = {(const float*)d_in[5],  (const float*)d_in[10], (const float*)d_in[15], (const float*)d_in[20]};
    const float* col_w = (const float*)d_in[21];
    const float* col_g = (const float*)d_in[22];
    const float* col_b = (const float*)d_in[23];
    const float* col_m = (const float*)d_in[24];
    const float* col_v = (const float*)d_in[25];
    const float* c5_w = (const float*)d_in[26]; const float* c5_g = (const float*)d_in[27];
    const float* c5_b = (const float*)d_in[28]; const float* c5_m = (const float*)d_in[29];
    const float* c5_v = (const float*)d_in[30];
    const float* c6_w = (const float*)d_in[31]; const float* c6_g = (const float*)d_in[32];
    const float* c6_b = (const float*)d_in[33]; const float* c6_m = (const float*)d_in[34];
    const float* c6_v = (const float*)d_in[35];
    const float* c7_w = (const float*)d_in[36]; const float* c7_g = (const float*)d_in[37];
    const float* c7_b = (const float*)d_in[38]; const float* c7_m = (const float*)d_in[39];
    const float* c7_v = (const float*)d_in[40];
    const float* c8_w = (const float*)d_in[41]; const float* c8_b = (const float*)d_in[42];

    // workspace layout (floats). Peak live set: x6 + xcomb = 120 MiB.
    float* ws    = (float*)d_ws;
    float* x6    = ws;                         // [0, 8388608)  (B*N x 512), written at c6
    float* xcomb = ws + 8388608;               // (B*N x 1408): cols 0-383 x_cat, 384-1407 x5
    float* x7    = xcomb;                      // reuse xcomb after c6 (B*N x 256)
    // early-phase aliases inside the (later) x6 region — all dead before c6 runs:
    float* xyzT  = ws;                         // (B*N x 6)      [0, 98304)
    float* xx    = ws + 98304;                 // (B*N)          [98304, 114688)
    int*   idxb  = (int*)(ws + 114688);        // (B*N x 20)     [114688, 442368)
    float* wtbuf = ws + 442368;                // up to 16384    [442368, 458752)
    float* pval  = ws + 458752;                // (B*N x 8 x 20) [458752, 3080192)
    int*   pidx  = (int*)(ws + 3080192);       // (B*N x 8 x 20) [3080192, 5701632)

    float* out_logits = (float*)d_out;                               // (B,N,13)
    float* out_x5     = (float*)d_out + (size_t)NBATCH * NPTS * 13;  // (B,1024,N)

    dim3 blk(256);
    dim3 knn_grid(NTOT / 64, NCHUNK);

    k_transpose_in<<<dim3(NTOT/256), blk, 0, stream>>>(x, xyzT);

    // ---- ec1: input xyz (C=3, stride 6) -> xcomb cols 0..63 ----
    k_row_norms<<<dim3(NTOT/256), blk, 0, stream>>>(xyzT, 6, 3, xx);
    k_knn_tile<4><<<knn_grid, blk, 0, stream>>>(xyzT, 6, 3, xx, pval, pidx);
    k_knn_merge<<<dim3(NTOT/256), blk, 0, stream>>>(pval, pidx, idxb);
    k_transpose_w<<<dim3((64*6+255)/256), blk, 0, stream>>>(ew[0], wtbuf, 64, 6);
    k_edge_conv<3,64><<<dim3(NTOT), blk, 0, stream>>>(xyzT, 6, idxb, wtbuf,
        eg[0], ebp[0], em[0], ev[0], xcomb + 0, 1408);

    // ---- ec2: x1 (cols 0..63) -> cols 64..127 ----
    k_row_norms<<<dim3(NTOT/256), blk, 0, stream>>>(xcomb + 0, 1408, 64, xx);
    k_knn_tile<64><<<knn_grid, blk, 0, stream>>>(xcomb + 0, 1408, 64, xx, pval, pidx);
    k_knn_merge<<<dim3(NTOT/256), blk, 0, stream>>>(pval, pidx, idxb);
    k_transpose_w<<<dim3((64*128+255)/256), blk, 0, stream>>>(ew[1], wtbuf, 64, 128);
    k_edge_conv<64,64><<<dim3(NTOT), blk, 0, stream>>>(xcomb + 0, 1408, idxb, wtbuf,
        eg[1], ebp[1], em[1], ev[1], xcomb + 64, 1408);

    // ---- ec3: x2 (cols 64..127) -> cols 128..191 ----
    k_row_norms<<<dim3(NTOT/256), blk, 0, stream>>>(xcomb + 64, 1408, 64, xx);
    k_knn_tile<64><<<knn_grid, blk, 0, stream>>>(xcomb + 64, 1408, 64, xx, pval, pidx);
    k_knn_merge<<<dim3(NTOT/256), blk, 0, stream>>>(pval, pidx, idxb);
    k_transpose_w<<<dim3((64*128+255)/256), blk, 0, stream>>>(ew[2], wtbuf, 64, 128);
    k_edge_conv<64,64><<<dim3(NTOT), blk, 0, stream>>>(xcomb + 64, 1408, idxb, wtbuf,
        eg[2], ebp[2], em[2], ev[2], xcomb + 128, 1408);

    // ---- ec4: x3 (cols 128..191) -> cols 192..319 (O=128) ----
    k_row_norms<<<dim3(NTOT/256), blk, 0, stream>>>(xcomb + 128, 1408, 64, xx);
    k_knn_tile<64><<<knn_grid, blk, 0, stream>>>(xcomb + 128, 1408, 64, xx, pval, pidx);
    k_knn_merge<<<dim3(NTOT/256), blk, 0, stream>>>(pval, pidx, idxb);
    k_transpose_w<<<dim3((128*128+255)/256), blk, 0, stream>>>(ew[3], wtbuf, 128, 128);
    k_edge_conv<64,128><<<dim3(NTOT), blk, 0, stream>>>(xcomb + 128, 1408, idxb, wtbuf,
        eg[3], ebp[3], em[3], ev[3], xcomb + 192, 1408);

    // ---- color: rgb -> cols 320..383 ----
    k_color<<<dim3(NTOT*64/256), blk, 0, stream>>>(xyzT, col_w, col_g, col_b, col_m, col_v,
        xcomb + 320, 1408);

    // ---- c5: (384 -> 1024), out into xcomb cols 384..1407 ----
    k_gemm<<<dim3(NTOT/64, 1024/64), blk, 0, stream>>>(xcomb, 1408, c5_w,
        c5_g, c5_b, c5_m, c5_v, 1, xcomb + 384, 1408, 384, 1024);
    k_transpose_x5<<<dim3(NTOT/64, 1024/64), blk, 0, stream>>>(xcomb, out_x5);

    // ---- c6: (1408 -> 512) ----
    k_gemm<<<dim3(NTOT/64, 512/64), blk, 0, stream>>>(xcomb, 1408, c6_w,
        c6_g, c6_b, c6_m, c6_v, 1, x6, 512, 1408, 512);

    // ---- c7: (512 -> 256) ----
    k_gemm<<<dim3(NTOT/64, 256/64), blk, 0, stream>>>(x6, 512, c7_w,
        c7_g, c7_b, c7_m, c7_v, 1, x7, 256, 512, 256);

    // ---- c8: (256 -> 13) + bias, straight into d_out (B,N,13) ----
    k_gemm<<<dim3(NTOT/64, 1), blk, 0, stream>>>(x7, 256, c8_w,
        nullptr, c8_b, nullptr, nullptr, 0, out_logits, 13, 256, 13);
}